// Round 14
// baseline (564.586 us; speedup 1.0000x reference)
//
#include <hip/hip_runtime.h>
#include <hip/hip_bf16.h>
#include <hip/hip_fp16.h>

#define IN_DIM 256
#define HDIM 128
#define CDIM 32
#define NSUB 512
#define PCHUNK 4096

typedef __attribute__((ext_vector_type(8))) unsigned short u16x8;
typedef __attribute__((ext_vector_type(8))) _Float16 f16x8;
typedef __attribute__((ext_vector_type(4))) float f32x4;
typedef __attribute__((ext_vector_type(4))) int int4v;

__device__ __forceinline__ int swz4(int r) { return (r & 3) ^ ((r >> 2) & 3); }

// ---------------- hierarchical CSR build (no per-edge global atomics) ----------------

__global__ void zero512_kernel(int* __restrict__ p) {
    p[blockIdx.x * 256 + threadIdx.x] = 0;
}

__global__ __launch_bounds__(256) void hist512_kernel(const int* __restrict__ dst,
                                                      int* __restrict__ cnt512, int e, int nsr) {
    __shared__ int h[NSUB];
    for (int j = threadIdx.x; j < NSUB; j += 256) h[j] = 0;
    __syncthreads();
    const int stride = gridDim.x * 256;
    for (int i = blockIdx.x * 256 + threadIdx.x; i < e; i += stride) {
        int d = __builtin_nontemporal_load(&dst[i]);
        atomicAdd(&h[(unsigned)d / (unsigned)nsr], 1);
    }
    __syncthreads();
    for (int j = threadIdx.x; j < NSUB; j += 256)
        if (h[j]) atomicAdd(&cnt512[j], h[j]);
}

__global__ __launch_bounds__(256) void scan512_kernel(const int* __restrict__ cnt512,
                                                      int* __restrict__ rp512,
                                                      int* __restrict__ rcur512, int e) {
    __shared__ int sd[256];
    int t = threadIdx.x;
    int v0 = cnt512[2 * t], v1 = cnt512[2 * t + 1];
    sd[t] = v0 + v1;
    __syncthreads();
    for (int off = 1; off < 256; off <<= 1) {
        int x = (t >= off) ? sd[t - off] : 0;
        __syncthreads();
        sd[t] += x;
        __syncthreads();
    }
    int excl = sd[t] - (v0 + v1);
    rp512[2 * t] = excl;          rcur512[2 * t] = excl;
    rp512[2 * t + 1] = excl + v0; rcur512[2 * t + 1] = excl + v0;
    if (t == 255) rp512[512] = e;
}

__global__ __launch_bounds__(256) void part512_kernel(
        const int* __restrict__ src, const int* __restrict__ dst,
        int* __restrict__ rcur512, long long* __restrict__ parts, int e, int nsr) {
    __shared__ long long staged[PCHUNK];           // 32 KB
    __shared__ int hist[NSUB], lbase[NSUB], gbase[NSUB], lcur[NSUB];
    __shared__ int sd[256];
    const int t = threadIdx.x;
    const int nch = (e + PCHUNK - 1) / PCHUNK;
    for (int c = blockIdx.x; c < nch; c += gridDim.x) {
        const int b0 = c * PCHUNK;
        const int cnt = (b0 + PCHUNK <= e) ? PCHUNK : (e - b0);
        int s[16], d[16], bn[16];
        hist[2 * t] = 0; hist[2 * t + 1] = 0;
        __syncthreads();
        if (cnt == PCHUNK) {
#pragma unroll
            for (int q = 0; q < 4; ++q) {
                int u = q * 256 + t;
                int4v sv = __builtin_nontemporal_load((const int4v*)(src + b0) + u);
                int4v dv = __builtin_nontemporal_load((const int4v*)(dst + b0) + u);
                s[4 * q] = sv.x; s[4 * q + 1] = sv.y; s[4 * q + 2] = sv.z; s[4 * q + 3] = sv.w;
                d[4 * q] = dv.x; d[4 * q + 1] = dv.y; d[4 * q + 2] = dv.z; d[4 * q + 3] = dv.w;
            }
#pragma unroll
            for (int j = 0; j < 16; ++j) {
                bn[j] = (int)((unsigned)d[j] / (unsigned)nsr);
                atomicAdd(&hist[bn[j]], 1);
            }
        } else {
#pragma unroll
            for (int j = 0; j < 16; ++j) {
                int u = (j / 4) * 1024 + t * 4 + (j & 3);
                int i = b0 + u;
                if (u < cnt) {
                    s[j] = src[i]; d[j] = dst[i];
                    bn[j] = (int)((unsigned)d[j] / (unsigned)nsr);
                    atomicAdd(&hist[bn[j]], 1);
                } else bn[j] = -1;
            }
        }
        __syncthreads();
        int h0 = hist[2 * t], h1 = hist[2 * t + 1];
        sd[t] = h0 + h1;
        __syncthreads();
        for (int off = 1; off < 256; off <<= 1) {
            int x = (t >= off) ? sd[t - off] : 0;
            __syncthreads();
            sd[t] += x;
            __syncthreads();
        }
        int excl = sd[t] - (h0 + h1);
        lbase[2 * t] = excl;          lcur[2 * t] = excl;
        lbase[2 * t + 1] = excl + h0; lcur[2 * t + 1] = excl + h0;
        gbase[2 * t]     = h0 ? atomicAdd(&rcur512[2 * t], h0) : 0;
        gbase[2 * t + 1] = h1 ? atomicAdd(&rcur512[2 * t + 1], h1) : 0;
        __syncthreads();
#pragma unroll
        for (int j = 0; j < 16; ++j) {
            if (bn[j] >= 0) {
                int pos = atomicAdd(&lcur[bn[j]], 1);
                staged[pos] = ((long long)(unsigned)d[j] << 32) | (unsigned)s[j];
            }
        }
        __syncthreads();
        for (int i = t; i < cnt; i += 256) {
            long long v = staged[i];
            int b = (int)((unsigned)(int)(v >> 32) / (unsigned)nsr);
            parts[gbase[b] + (i - lbase[b])] = v;
        }
        __syncthreads();
    }
}

__global__ __launch_bounds__(256) void sortplace_kernel(
        const long long* __restrict__ parts, const int* __restrict__ rp512,
        int* __restrict__ row_ptr, int* __restrict__ csr_src, float* __restrict__ dinv,
        int n, int nsr) {
    __shared__ int hist[256], sd[256], cur[256];
    const int b = blockIdx.x;
    const int d0 = b * nsr;
    if (d0 > n) return;
    const int i0 = rp512[b], iE = rp512[b + 1];
    const int t = threadIdx.x;
    hist[t] = 0;
    __syncthreads();
    for (int i = i0 + t; i < iE; i += 256) {
        int d = (int)(parts[i] >> 32);
        atomicAdd(&hist[d - d0], 1);
    }
    __syncthreads();
    int v = hist[t];
    sd[t] = v;
    __syncthreads();
    for (int off = 1; off < 256; off <<= 1) {
        int x = (t >= off) ? sd[t - off] : 0;
        __syncthreads();
        sd[t] += x;
        __syncthreads();
    }
    int excl = sd[t] - v;
    int node = d0 + t;
    if (t <= nsr && node <= n) row_ptr[node] = i0 + excl;
    if (t < nsr && node < n) dinv[node] = rsqrtf((float)(v + 1));  // +1 self-loop
    cur[t] = i0 + excl;
    __syncthreads();
    for (int i = i0 + t; i < iE; i += 256) {
        long long vv = parts[i];
        int d = (int)(vv >> 32);
        int pos = atomicAdd(&cur[d - d0], 1);
        csr_src[pos] = (int)(vv & 0xffffffffLL);
    }
}

// ---------------- fused weight convert+transpose (all 3 weights, one launch) ----------------

__global__ void wconv_all_kernel(const float* __restrict__ W1, const float* __restrict__ W2,
                                 const float* __restrict__ Wc,
                                 unsigned short* __restrict__ w1t, unsigned short* __restrict__ w2t,
                                 unsigned short* __restrict__ wct) {
    int i = blockIdx.x * 256 + threadIdx.x;
    const int s1 = IN_DIM * HDIM;
    const int s2 = s1 + HDIM * HDIM;
    const int s3 = s2 + HDIM * CDIM;
    if (i < s1) {
        int k = i / HDIM, n2 = i % HDIM;
        w1t[n2 * IN_DIM + k] = __half_as_ushort(__float2half_rn(W1[i]));
    } else if (i < s2) {
        int j = i - s1; int k = j / HDIM, n2 = j % HDIM;
        w2t[n2 * HDIM + k] = __half_as_ushort(__float2half_rn(W2[j]));
    } else if (i < s3) {
        int j = i - s2; int k = j / CDIM, n2 = j % CDIM;
        wct[n2 * HDIM + k] = __half_as_ushort(__float2half_rn(Wc[j]));
    }
}

// ---------------- fp16 MFMA GEMM ----------------
// AMODE: 0 = fp32 row-major, 1 = fp16 column-blocked [g][M][16]
// OMODE: 0 = fp32 row-major (stride BN), 1 = fp16 column-blocked

template<int BN, int AMODE, bool BIAS, int OMODE>
__global__ __launch_bounds__(256) void gemm_f16_kernel(
        const void* __restrict__ Ap, const unsigned short* __restrict__ Wt,
        const float* __restrict__ bias, void* __restrict__ C, int M, int K) {
    constexpr int FM = 4;
    constexpr int FN = BN / 2 / 16;
    constexpr int BU = (BN * 4 + 255) / 256;
    __shared__ __align__(16) unsigned short As[2][128 * 32];
    __shared__ __align__(16) unsigned short Bs[2][BN * 32];

    const int t = threadIdx.x;
    const int rowBase = blockIdx.x * 128;
    const int l = t & 63, w = t >> 6;
    const int wr = w >> 1, wc = w & 1;
    const int lrow = l & 15, g = l >> 4;
    const int NK = K >> 5;

    f32x4 acc[FM][FN];
#pragma unroll
    for (int i = 0; i < FM; ++i)
#pragma unroll
        for (int j = 0; j < FN; ++j) acc[i][j] = f32x4{0.f, 0.f, 0.f, 0.f};

    u16x8 aS[2];
    float4 af[2][2];
    u16x8 bS[BU];

    auto LOADA = [&](int k0) {
#pragma unroll
        for (int i = 0; i < 2; ++i) {
            int u = t + 256 * i;
            int r = u >> 2, c = u & 3;
            int gr = rowBase + r; if (gr > M - 1) gr = M - 1;
            if (AMODE == 1) {
                int colbase = k0 + c * 8;
                aS[i] = ((const u16x8*)Ap)[((size_t)(colbase >> 4) * M + gr) * 2 + ((colbase >> 3) & 1)];
            } else {
                const float4* ar = (const float4*)((const float*)Ap + (size_t)gr * K + k0);
                af[i][0] = ar[c * 2];
                af[i][1] = ar[c * 2 + 1];
            }
        }
    };
    auto WRITEA = [&](int buf) {
#pragma unroll
        for (int i = 0; i < 2; ++i) {
            int u = t + 256 * i;
            int r = u >> 2, c = u & 3;
            int d = r * 4 + (c ^ swz4(r));
            if (AMODE == 1) {
                ((u16x8*)As[buf])[d] = aS[i];
            } else {
                f16x8 h;
                h[0] = (_Float16)af[i][0].x; h[1] = (_Float16)af[i][0].y;
                h[2] = (_Float16)af[i][0].z; h[3] = (_Float16)af[i][0].w;
                h[4] = (_Float16)af[i][1].x; h[5] = (_Float16)af[i][1].y;
                h[6] = (_Float16)af[i][1].z; h[7] = (_Float16)af[i][1].w;
                ((f16x8*)As[buf])[d] = h;
            }
        }
    };
    auto LOADB = [&](int k0) {
#pragma unroll
        for (int i = 0; i < BU; ++i) {
            int u = t + 256 * i;
            if (u < BN * 4) {
                int nn = u >> 2, c = u & 3;
                bS[i] = ((const u16x8*)(Wt + (size_t)nn * K + k0))[c];
            }
        }
    };
    auto WRITEB = [&](int buf) {
#pragma unroll
        for (int i = 0; i < BU; ++i) {
            int u = t + 256 * i;
            if (u < BN * 4) {
                int nn = u >> 2, c = u & 3;
                ((u16x8*)Bs[buf])[nn * 4 + (c ^ swz4(nn))] = bS[i];
            }
        }
    };

    LOADA(0); LOADB(0);
    WRITEA(0); WRITEB(0);
    __syncthreads();

    for (int k = 0; k < NK; ++k) {
        int cur = k & 1;
        bool more = (k + 1 < NK);
        if (more) { LOADA((k + 1) << 5); LOADB((k + 1) << 5); }

        f16x8 a[FM], b[FN];
#pragma unroll
        for (int fm = 0; fm < FM; ++fm) {
            int r = wr * 64 + fm * 16 + lrow;
            a[fm] = ((const f16x8*)As[cur])[r * 4 + (g ^ swz4(r))];
        }
#pragma unroll
        for (int fn = 0; fn < FN; ++fn) {
            int nn = wc * (FN * 16) + fn * 16 + lrow;
            b[fn] = ((const f16x8*)Bs[cur])[nn * 4 + (g ^ swz4(nn))];
        }
#pragma unroll
        for (int fm = 0; fm < FM; ++fm)
#pragma unroll
            for (int fn = 0; fn < FN; ++fn)
                acc[fm][fn] = __builtin_amdgcn_mfma_f32_16x16x32_f16(a[fm], b[fn], acc[fm][fn], 0, 0, 0);

        if (more) { WRITEA(cur ^ 1); WRITEB(cur ^ 1); }
        __syncthreads();
    }

#pragma unroll
    for (int fm = 0; fm < FM; ++fm)
#pragma unroll
        for (int fn = 0; fn < FN; ++fn) {
            int col = wc * (FN * 16) + fn * 16 + lrow;
#pragma unroll
            for (int r = 0; r < 4; ++r) {
                int row = rowBase + wr * 64 + fm * 16 + g * 4 + r;
                if (row < M) {
                    float v = acc[fm][fn][r];
                    if (BIAS) v += bias[col];
                    if (OMODE == 1) {
                        __builtin_nontemporal_store(
                            __half_as_ushort(__float2half_rn(v)),
                            (unsigned short*)C + ((size_t)(col >> 4) * M + row) * 16 + (col & 15));
                    } else {
                        ((float*)C)[(size_t)row * BN + col] = v;
                    }
                }
            }
        }
}

// ---------------- column-blocked gather, wave-per-(node,group), edge-slot parallel ----------------
// x stored [8 groups][n][16 cols] fp16. Block group g = blockIdx&7 (round-robin -> XCD g):
// its 3.2 MB slice stays L2-resident. Wave = 1 node: 64 lanes = 8 edge-slots x 8 col-lanes;
// slot k does edges p0+k, p0+k+8, ... (no divergence); shfl-reduce across slots at end.

__global__ __launch_bounds__(256) void gather_cb_kernel(
        const __half* __restrict__ xcb, const int* __restrict__ row_ptr,
        const int* __restrict__ csr_src, const float* __restrict__ dinv,
        const float* __restrict__ bias, __half* __restrict__ outcb, int n) {
    const int g = blockIdx.x & 7;
    const int w = threadIdx.x >> 6;
    const int lane = threadIdx.x & 63;
    const int slot = lane >> 3, cl = lane & 7;
    const int node = (blockIdx.x >> 3) * 4 + w;
    if (node >= n) return;
    const __half2* xs = (const __half2*)xcb + (size_t)g * n * 8;
    float ax = 0.f, ay = 0.f;
    const int p0 = row_ptr[node], end = row_ptr[node + 1];
    int p = p0 + slot;
    for (; p + 8 < end; p += 16) {
        int s0 = csr_src[p], s1 = csr_src[p + 8];
        float w0 = dinv[s0], w1 = dinv[s1];
        float2 v0 = __half22float2(xs[(size_t)s0 * 8 + cl]);
        float2 v1 = __half22float2(xs[(size_t)s1 * 8 + cl]);
        ax += w0 * v0.x + w1 * v1.x;
        ay += w0 * v0.y + w1 * v1.y;
    }
    if (p < end) {
        int s0 = csr_src[p];
        float w0 = dinv[s0];
        float2 v0 = __half22float2(xs[(size_t)s0 * 8 + cl]);
        ax += w0 * v0.x;
        ay += w0 * v0.y;
    }
    // reduce across the 8 slots (lanes differing in bits 3..5)
    ax += __shfl_xor(ax, 8);  ay += __shfl_xor(ay, 8);
    ax += __shfl_xor(ax, 16); ay += __shfl_xor(ay, 16);
    ax += __shfl_xor(ax, 32); ay += __shfl_xor(ay, 32);
    if (slot == 0) {
        float dd = dinv[node];
        float2 self = __half22float2(xs[(size_t)node * 8 + cl]);
        ax += dd * self.x;
        ay += dd * self.y;
        float2 bb = ((const float2*)bias)[g * 8 + cl];
        float2 r;
        r.x = fmaxf(ax * dd + bb.x, 0.f);
        r.y = fmaxf(ay * dd + bb.y, 0.f);
        __half2 hv = __float22half2_rn(r);
        __builtin_nontemporal_store(*(unsigned int*)&hv,
            (unsigned int*)((__half2*)outcb + (size_t)g * n * 8 + (size_t)node * 8 + cl));
    }
}

// ---------------- launch ----------------

extern "C" void kernel_launch(void* const* d_in, const int* in_sizes, int n_in,
                              void* d_out, int out_size, void* d_ws, size_t ws_size,
                              hipStream_t stream) {
    const float* X  = (const float*)d_in[0];
    const int*   ei = (const int*)d_in[1];
    const float* W1 = (const float*)d_in[2];
    const float* b1 = (const float*)d_in[3];
    const float* W2 = (const float*)d_in[4];
    const float* b2 = (const float*)d_in[5];
    const float* Wc = (const float*)d_in[6];
    const float* bc = (const float*)d_in[7];
    float* out = (float*)d_out;

    const int n = in_sizes[0] / IN_DIM;   // 100000
    const int e = in_sizes[1] / 2;        // 1600000
    const int* src = ei;
    const int* dst = ei + e;
    const int nsr = (n + NSUB - 1) / NSUB;  // sub-range size (196)

    // workspace layout
    char* ws = (char*)d_ws;
    auto align = [](size_t x) { return (x + 255) & ~(size_t)255; };
    size_t off = 0;
    float* dinv   = (float*)(ws + off); off += align((size_t)n * 4);
    int* row_ptr  = (int*)(ws + off);   off += align((size_t)(n + 1) * 4);
    int* cnt512   = (int*)(ws + off);   off += align(512 * 4);
    int* rp512    = (int*)(ws + off);   off += align(513 * 4);
    int* rcur512  = (int*)(ws + off);   off += align(512 * 4);
    long long* parts = (long long*)(ws + off); off += align((size_t)e * 8);
    int* csr_src  = (int*)(ws + off);   off += align((size_t)e * 4);
    unsigned short* w1t = (unsigned short*)(ws + off); off += align((size_t)IN_DIM * HDIM * 2);
    unsigned short* w2t = (unsigned short*)(ws + off); off += align((size_t)HDIM * HDIM * 2);
    unsigned short* wct = (unsigned short*)(ws + off); off += align((size_t)HDIM * CDIM * 2);
    __half* bufAh = (__half*)(ws + off); off += align((size_t)n * HDIM * 2);
    __half* bufBh = (__half*)(ws + off); off += align((size_t)n * HDIM * 2);

    // ---- weights (one launch) ----
    wconv_all_kernel<<<(IN_DIM * HDIM + HDIM * HDIM + HDIM * CDIM + 255) / 256, 256, 0, stream>>>(
        W1, W2, Wc, w1t, w2t, wct);

    // ---- hierarchical CSR build (shared by both layers) ----
    zero512_kernel<<<2, 256, 0, stream>>>(cnt512);
    hist512_kernel<<<256, 256, 0, stream>>>(dst, cnt512, e, nsr);
    scan512_kernel<<<1, 256, 0, stream>>>(cnt512, rp512, rcur512, e);
    part512_kernel<<<512, 256, 0, stream>>>(src, dst, rcur512, parts, e, nsr);
    sortplace_kernel<<<NSUB, 256, 0, stream>>>(parts, rp512, row_ptr, csr_src, dinv, n, nsr);

    const int gBlocks = (n + 127) / 128;
    const int gaBlocks = ((n + 3) / 4) * 8;   // 8 groups x (4 nodes per block)

    // layer 1: fp32 X (row-major) -> fp16 col-blocked
    gemm_f16_kernel<128, 0, false, 1><<<gBlocks, 256, 0, stream>>>(X, w1t, nullptr, bufAh, n, IN_DIM);
    gather_cb_kernel<<<gaBlocks, 256, 0, stream>>>(bufAh, row_ptr, csr_src, dinv, b1, bufBh, n);

    // layer 2: fp16 col-blocked -> fp16 col-blocked
    gemm_f16_kernel<128, 1, false, 1><<<gBlocks, 256, 0, stream>>>(bufBh, w2t, nullptr, bufAh, n, HDIM);
    gather_cb_kernel<<<gaBlocks, 256, 0, stream>>>(bufAh, row_ptr, csr_src, dinv, b2, bufBh, n);

    // classifier: fp16 col-blocked -> fp32 row-major out, fused bias
    gemm_f16_kernel<32, 1, true, 0><<<gBlocks, 256, 0, stream>>>(bufBh, wct, bc, out, n, HDIM);
}

// Round 15
// 248.974 us; speedup vs baseline: 2.2677x; 2.2677x over previous
//
#include <hip/hip_runtime.h>
#include <hip/hip_bf16.h>
#include <hip/hip_fp16.h>

#define IN_DIM 256
#define HDIM 128
#define CDIM 32
#define NSUB 512
#define PCHUNK 4096

typedef __attribute__((ext_vector_type(8))) unsigned short u16x8;
typedef __attribute__((ext_vector_type(8))) _Float16 f16x8;
typedef __attribute__((ext_vector_type(4))) float f32x4;
typedef __attribute__((ext_vector_type(4))) int int4v;

__device__ __forceinline__ int swz4(int r) { return (r & 3) ^ ((r >> 2) & 3); }

// ---------------- hierarchical CSR build (no per-edge global atomics) ----------------

__global__ void zero512_kernel(int* __restrict__ p) {
    p[blockIdx.x * 256 + threadIdx.x] = 0;
}

__global__ __launch_bounds__(256) void hist512_kernel(const int* __restrict__ dst,
                                                      int* __restrict__ cnt512, int e, int nsr) {
    __shared__ int h[NSUB];
    for (int j = threadIdx.x; j < NSUB; j += 256) h[j] = 0;
    __syncthreads();
    const int stride = gridDim.x * 256;
    for (int i = blockIdx.x * 256 + threadIdx.x; i < e; i += stride) {
        int d = __builtin_nontemporal_load(&dst[i]);
        atomicAdd(&h[(unsigned)d / (unsigned)nsr], 1);
    }
    __syncthreads();
    for (int j = threadIdx.x; j < NSUB; j += 256)
        if (h[j]) atomicAdd(&cnt512[j], h[j]);
}

__global__ __launch_bounds__(256) void scan512_kernel(const int* __restrict__ cnt512,
                                                      int* __restrict__ rp512,
                                                      int* __restrict__ rcur512, int e) {
    __shared__ int sd[256];
    int t = threadIdx.x;
    int v0 = cnt512[2 * t], v1 = cnt512[2 * t + 1];
    sd[t] = v0 + v1;
    __syncthreads();
    for (int off = 1; off < 256; off <<= 1) {
        int x = (t >= off) ? sd[t - off] : 0;
        __syncthreads();
        sd[t] += x;
        __syncthreads();
    }
    int excl = sd[t] - (v0 + v1);
    rp512[2 * t] = excl;          rcur512[2 * t] = excl;
    rp512[2 * t + 1] = excl + v0; rcur512[2 * t + 1] = excl + v0;
    if (t == 255) rp512[512] = e;
}

__global__ __launch_bounds__(256) void part512_kernel(
        const int* __restrict__ src, const int* __restrict__ dst,
        int* __restrict__ rcur512, long long* __restrict__ parts, int e, int nsr) {
    __shared__ long long staged[PCHUNK];           // 32 KB
    __shared__ int hist[NSUB], lbase[NSUB], gbase[NSUB], lcur[NSUB];
    __shared__ int sd[256];
    const int t = threadIdx.x;
    const int nch = (e + PCHUNK - 1) / PCHUNK;
    for (int c = blockIdx.x; c < nch; c += gridDim.x) {
        const int b0 = c * PCHUNK;
        const int cnt = (b0 + PCHUNK <= e) ? PCHUNK : (e - b0);
        int s[16], d[16], bn[16];
        hist[2 * t] = 0; hist[2 * t + 1] = 0;
        __syncthreads();
        if (cnt == PCHUNK) {
#pragma unroll
            for (int q = 0; q < 4; ++q) {
                int u = q * 256 + t;
                int4v sv = __builtin_nontemporal_load((const int4v*)(src + b0) + u);
                int4v dv = __builtin_nontemporal_load((const int4v*)(dst + b0) + u);
                s[4 * q] = sv.x; s[4 * q + 1] = sv.y; s[4 * q + 2] = sv.z; s[4 * q + 3] = sv.w;
                d[4 * q] = dv.x; d[4 * q + 1] = dv.y; d[4 * q + 2] = dv.z; d[4 * q + 3] = dv.w;
            }
#pragma unroll
            for (int j = 0; j < 16; ++j) {
                bn[j] = (int)((unsigned)d[j] / (unsigned)nsr);
                atomicAdd(&hist[bn[j]], 1);
            }
        } else {
#pragma unroll
            for (int j = 0; j < 16; ++j) {
                int u = (j / 4) * 1024 + t * 4 + (j & 3);
                int i = b0 + u;
                if (u < cnt) {
                    s[j] = src[i]; d[j] = dst[i];
                    bn[j] = (int)((unsigned)d[j] / (unsigned)nsr);
                    atomicAdd(&hist[bn[j]], 1);
                } else bn[j] = -1;
            }
        }
        __syncthreads();
        int h0 = hist[2 * t], h1 = hist[2 * t + 1];
        sd[t] = h0 + h1;
        __syncthreads();
        for (int off = 1; off < 256; off <<= 1) {
            int x = (t >= off) ? sd[t - off] : 0;
            __syncthreads();
            sd[t] += x;
            __syncthreads();
        }
        int excl = sd[t] - (h0 + h1);
        lbase[2 * t] = excl;          lcur[2 * t] = excl;
        lbase[2 * t + 1] = excl + h0; lcur[2 * t + 1] = excl + h0;
        gbase[2 * t]     = h0 ? atomicAdd(&rcur512[2 * t], h0) : 0;
        gbase[2 * t + 1] = h1 ? atomicAdd(&rcur512[2 * t + 1], h1) : 0;
        __syncthreads();
#pragma unroll
        for (int j = 0; j < 16; ++j) {
            if (bn[j] >= 0) {
                int pos = atomicAdd(&lcur[bn[j]], 1);
                staged[pos] = ((long long)(unsigned)d[j] << 32) | (unsigned)s[j];
            }
        }
        __syncthreads();
        for (int i = t; i < cnt; i += 256) {
            long long v = staged[i];
            int b = (int)((unsigned)(int)(v >> 32) / (unsigned)nsr);
            parts[gbase[b] + (i - lbase[b])] = v;
        }
        __syncthreads();
    }
}

__global__ __launch_bounds__(256) void sortplace_kernel(
        const long long* __restrict__ parts, const int* __restrict__ rp512,
        int* __restrict__ row_ptr, int* __restrict__ csr_src, float* __restrict__ dinv,
        int n, int nsr) {
    __shared__ int hist[256], sd[256], cur[256];
    const int b = blockIdx.x;
    const int d0 = b * nsr;
    if (d0 > n) return;
    const int i0 = rp512[b], iE = rp512[b + 1];
    const int t = threadIdx.x;
    hist[t] = 0;
    __syncthreads();
    for (int i = i0 + t; i < iE; i += 256) {
        int d = (int)(parts[i] >> 32);
        atomicAdd(&hist[d - d0], 1);
    }
    __syncthreads();
    int v = hist[t];
    sd[t] = v;
    __syncthreads();
    for (int off = 1; off < 256; off <<= 1) {
        int x = (t >= off) ? sd[t - off] : 0;
        __syncthreads();
        sd[t] += x;
        __syncthreads();
    }
    int excl = sd[t] - v;
    int node = d0 + t;
    if (t <= nsr && node <= n) row_ptr[node] = i0 + excl;
    if (t < nsr && node < n) dinv[node] = rsqrtf((float)(v + 1));  // +1 self-loop
    cur[t] = i0 + excl;
    __syncthreads();
    for (int i = i0 + t; i < iE; i += 256) {
        long long vv = parts[i];
        int d = (int)(vv >> 32);
        int pos = atomicAdd(&cur[d - d0], 1);
        csr_src[pos] = (int)(vv & 0xffffffffLL);
    }
}

// ---------------- fused weight convert+transpose (all 3 weights, one launch) ----------------

__global__ void wconv_all_kernel(const float* __restrict__ W1, const float* __restrict__ W2,
                                 const float* __restrict__ Wc,
                                 unsigned short* __restrict__ w1t, unsigned short* __restrict__ w2t,
                                 unsigned short* __restrict__ wct) {
    int i = blockIdx.x * 256 + threadIdx.x;
    const int s1 = IN_DIM * HDIM;
    const int s2 = s1 + HDIM * HDIM;
    const int s3 = s2 + HDIM * CDIM;
    if (i < s1) {
        int k = i / HDIM, n2 = i % HDIM;
        w1t[n2 * IN_DIM + k] = __half_as_ushort(__float2half_rn(W1[i]));
    } else if (i < s2) {
        int j = i - s1; int k = j / HDIM, n2 = j % HDIM;
        w2t[n2 * HDIM + k] = __half_as_ushort(__float2half_rn(W2[j]));
    } else if (i < s3) {
        int j = i - s2; int k = j / CDIM, n2 = j % CDIM;
        wct[n2 * HDIM + k] = __half_as_ushort(__float2half_rn(Wc[j]));
    }
}

// ---------------- fp16 MFMA GEMM: C = A(MxK) @ Wt^T, 128xBN tile, BK=32, dbuf LDS ----------------

template<int BN, bool AF16, bool BIAS, bool OUTH>
__global__ __launch_bounds__(256) void gemm_f16_kernel(
        const void* __restrict__ Ap, const unsigned short* __restrict__ Wt,
        const float* __restrict__ bias, void* __restrict__ C, int M, int K) {
    constexpr int FM = 4;
    constexpr int FN = BN / 2 / 16;
    constexpr int BU = (BN * 4 + 255) / 256;
    __shared__ __align__(16) unsigned short As[2][128 * 32];
    __shared__ __align__(16) unsigned short Bs[2][BN * 32];

    const int t = threadIdx.x;
    const int rowBase = blockIdx.x * 128;
    const int l = t & 63, w = t >> 6;
    const int wr = w >> 1, wc = w & 1;
    const int lrow = l & 15, g = l >> 4;
    const int NK = K >> 5;

    f32x4 acc[FM][FN];
#pragma unroll
    for (int i = 0; i < FM; ++i)
#pragma unroll
        for (int j = 0; j < FN; ++j) acc[i][j] = f32x4{0.f, 0.f, 0.f, 0.f};

    u16x8 aS[2];
    float4 af[2][2];
    u16x8 bS[BU];

    auto LOADA = [&](int k0) {
#pragma unroll
        for (int i = 0; i < 2; ++i) {
            int u = t + 256 * i;
            int r = u >> 2, c = u & 3;
            int gr = rowBase + r; if (gr > M - 1) gr = M - 1;
            if (AF16) {
                aS[i] = ((const u16x8*)((const unsigned short*)Ap + (size_t)gr * K + k0))[c];
            } else {
                const float4* ar = (const float4*)((const float*)Ap + (size_t)gr * K + k0);
                af[i][0] = ar[c * 2];
                af[i][1] = ar[c * 2 + 1];
            }
        }
    };
    auto WRITEA = [&](int buf) {
#pragma unroll
        for (int i = 0; i < 2; ++i) {
            int u = t + 256 * i;
            int r = u >> 2, c = u & 3;
            int d = r * 4 + (c ^ swz4(r));
            if (AF16) {
                ((u16x8*)As[buf])[d] = aS[i];
            } else {
                f16x8 h;
                h[0] = (_Float16)af[i][0].x; h[1] = (_Float16)af[i][0].y;
                h[2] = (_Float16)af[i][0].z; h[3] = (_Float16)af[i][0].w;
                h[4] = (_Float16)af[i][1].x; h[5] = (_Float16)af[i][1].y;
                h[6] = (_Float16)af[i][1].z; h[7] = (_Float16)af[i][1].w;
                ((f16x8*)As[buf])[d] = h;
            }
        }
    };
    auto LOADB = [&](int k0) {
#pragma unroll
        for (int i = 0; i < BU; ++i) {
            int u = t + 256 * i;
            if (u < BN * 4) {
                int nn = u >> 2, c = u & 3;
                bS[i] = ((const u16x8*)(Wt + (size_t)nn * K + k0))[c];
            }
        }
    };
    auto WRITEB = [&](int buf) {
#pragma unroll
        for (int i = 0; i < BU; ++i) {
            int u = t + 256 * i;
            if (u < BN * 4) {
                int nn = u >> 2, c = u & 3;
                ((u16x8*)Bs[buf])[nn * 4 + (c ^ swz4(nn))] = bS[i];
            }
        }
    };

    LOADA(0); LOADB(0);
    WRITEA(0); WRITEB(0);
    __syncthreads();

    for (int k = 0; k < NK; ++k) {
        int cur = k & 1;
        bool more = (k + 1 < NK);
        if (more) { LOADA((k + 1) << 5); LOADB((k + 1) << 5); }

        f16x8 a[FM], b[FN];
#pragma unroll
        for (int fm = 0; fm < FM; ++fm) {
            int r = wr * 64 + fm * 16 + lrow;
            a[fm] = ((const f16x8*)As[cur])[r * 4 + (g ^ swz4(r))];
        }
#pragma unroll
        for (int fn = 0; fn < FN; ++fn) {
            int nn = wc * (FN * 16) + fn * 16 + lrow;
            b[fn] = ((const f16x8*)Bs[cur])[nn * 4 + (g ^ swz4(nn))];
        }
#pragma unroll
        for (int fm = 0; fm < FM; ++fm)
#pragma unroll
            for (int fn = 0; fn < FN; ++fn)
                acc[fm][fn] = __builtin_amdgcn_mfma_f32_16x16x32_f16(a[fm], b[fn], acc[fm][fn], 0, 0, 0);

        if (more) { WRITEA(cur ^ 1); WRITEB(cur ^ 1); }
        __syncthreads();
    }

#pragma unroll
    for (int fm = 0; fm < FM; ++fm)
#pragma unroll
        for (int fn = 0; fn < FN; ++fn) {
            int col = wc * (FN * 16) + fn * 16 + lrow;
#pragma unroll
            for (int r = 0; r < 4; ++r) {
                int row = rowBase + wr * 64 + fm * 16 + g * 4 + r;
                if (row < M) {
                    float v = acc[fm][fn][r];
                    if (BIAS) v += bias[col];
                    if (OUTH) {
                        __builtin_nontemporal_store(
                            __half_as_ushort(__float2half_rn(v)),
                            (unsigned short*)C + (size_t)row * BN + col);
                    } else {
                        ((float*)C)[(size_t)row * BN + col] = v;
                    }
                }
            }
        }
}

// ---------------- gather aggregation (fp16 in/out; fused self-loop + bias + relu) ----------------

__global__ __launch_bounds__(256) void gather_kernel(
        const __half* __restrict__ x, const int* __restrict__ row_ptr,
        const int* __restrict__ csr_src, const float* __restrict__ dinv,
        const float* __restrict__ bias, __half* __restrict__ out, int n) {
    int node = __builtin_amdgcn_readfirstlane(blockIdx.x * 4 + (threadIdx.x >> 6));
    if (node >= n) return;
    int lane = threadIdx.x & 63;
    const __half2* xv = (const __half2*)x;   // row = 64 half2
    float dd = dinv[node];
    float2 self = __half22float2(xv[(size_t)node * 64 + lane]);
    float accx = dd * self.x, accy = dd * self.y;
    int p = row_ptr[node], end = row_ptr[node + 1];
    for (; p + 7 < end; p += 8) {
        int s[8]; float w[8]; float2 v[8];
#pragma unroll
        for (int j = 0; j < 8; ++j) s[j] = csr_src[p + j];
#pragma unroll
        for (int j = 0; j < 8; ++j) w[j] = dinv[s[j]];
#pragma unroll
        for (int j = 0; j < 8; ++j) v[j] = __half22float2(xv[(size_t)s[j] * 64 + lane]);
#pragma unroll
        for (int j = 0; j < 8; ++j) { accx += w[j] * v[j].x; accy += w[j] * v[j].y; }
    }
    for (; p + 3 < end; p += 4) {
        int s0 = csr_src[p], s1 = csr_src[p + 1], s2 = csr_src[p + 2], s3 = csr_src[p + 3];
        float w0 = dinv[s0], w1 = dinv[s1], w2 = dinv[s2], w3 = dinv[s3];
        float2 v0 = __half22float2(xv[(size_t)s0 * 64 + lane]);
        float2 v1 = __half22float2(xv[(size_t)s1 * 64 + lane]);
        float2 v2 = __half22float2(xv[(size_t)s2 * 64 + lane]);
        float2 v3 = __half22float2(xv[(size_t)s3 * 64 + lane]);
        accx += w0 * v0.x + w1 * v1.x + w2 * v2.x + w3 * v3.x;
        accy += w0 * v0.y + w1 * v1.y + w2 * v2.y + w3 * v3.y;
    }
    for (; p < end; ++p) {
        int s0 = csr_src[p];
        float w0 = dinv[s0];
        float2 v0 = __half22float2(xv[(size_t)s0 * 64 + lane]);
        accx += w0 * v0.x;
        accy += w0 * v0.y;
    }
    float2 bb = ((const float2*)bias)[lane];
    float2 r;
    r.x = fmaxf(accx * dd + bb.x, 0.f);
    r.y = fmaxf(accy * dd + bb.y, 0.f);
    __half2 hv = __float22half2_rn(r);
    __builtin_nontemporal_store(*(unsigned int*)&hv,
                                (unsigned int*)((__half2*)out + (size_t)node * 64 + lane));
}

// ---------------- fused gather2 + classifier ----------------

__global__ __launch_bounds__(256) void gather_cls_kernel(
        const __half* __restrict__ x, const int* __restrict__ row_ptr,
        const int* __restrict__ csr_src, const float* __restrict__ dinv,
        const float* __restrict__ b2, const unsigned short* __restrict__ wct,
        const float* __restrict__ bc, float* __restrict__ out, int n) {
    __shared__ __align__(16) __half h_lds[16][136];
    const int w = threadIdx.x >> 6;
    const int lane = threadIdx.x & 63;
    const int node0 = blockIdx.x * 16;
    const __half2* xv = (const __half2*)x;
    const float2 bb = ((const float2*)b2)[lane];

#pragma unroll
    for (int j = 0; j < 4; ++j) {
        int row = w * 4 + j;
        int node = __builtin_amdgcn_readfirstlane(node0 + row);
        float2 rv = make_float2(0.f, 0.f);
        if (node < n) {
            float dd = dinv[node];
            float2 self = __half22float2(xv[(size_t)node * 64 + lane]);
            float accx = dd * self.x, accy = dd * self.y;
            int p = row_ptr[node], end = row_ptr[node + 1];
            for (; p + 7 < end; p += 8) {
                int s[8]; float wt[8]; float2 v[8];
#pragma unroll
                for (int q = 0; q < 8; ++q) s[q] = csr_src[p + q];
#pragma unroll
                for (int q = 0; q < 8; ++q) wt[q] = dinv[s[q]];
#pragma unroll
                for (int q = 0; q < 8; ++q) v[q] = __half22float2(xv[(size_t)s[q] * 64 + lane]);
#pragma unroll
                for (int q = 0; q < 8; ++q) { accx += wt[q] * v[q].x; accy += wt[q] * v[q].y; }
            }
            for (; p + 3 < end; p += 4) {
                int s0 = csr_src[p], s1 = csr_src[p + 1], s2 = csr_src[p + 2], s3 = csr_src[p + 3];
                float w0 = dinv[s0], w1 = dinv[s1], w2 = dinv[s2], w3 = dinv[s3];
                float2 v0 = __half22float2(xv[(size_t)s0 * 64 + lane]);
                float2 v1 = __half22float2(xv[(size_t)s1 * 64 + lane]);
                float2 v2 = __half22float2(xv[(size_t)s2 * 64 + lane]);
                float2 v3 = __half22float2(xv[(size_t)s3 * 64 + lane]);
                accx += w0 * v0.x + w1 * v1.x + w2 * v2.x + w3 * v3.x;
                accy += w0 * v0.y + w1 * v1.y + w2 * v2.y + w3 * v3.y;
            }
            for (; p < end; ++p) {
                int s0 = csr_src[p];
                float w0 = dinv[s0];
                float2 v0 = __half22float2(xv[(size_t)s0 * 64 + lane]);
                accx += w0 * v0.x;
                accy += w0 * v0.y;
            }
            rv.x = fmaxf(accx * dd + bb.x, 0.f);
            rv.y = fmaxf(accy * dd + bb.y, 0.f);
        }
        *(__half2*)&h_lds[row][2 * lane] = __float22half2_rn(rv);
    }
    __syncthreads();

    if (w == 0) {
        const int lrow = lane & 15, g = lane >> 4;
        f32x4 acc[2];
        acc[0] = f32x4{0.f, 0.f, 0.f, 0.f};
        acc[1] = f32x4{0.f, 0.f, 0.f, 0.f};
#pragma unroll
        for (int k0 = 0; k0 < HDIM; k0 += 32) {
            f16x8 a = *(const f16x8*)&h_lds[lrow][k0 + 8 * g];
#pragma unroll
            for (int fn = 0; fn < 2; ++fn) {
                f16x8 b = *(const f16x8*)((const _Float16*)wct + (fn * 16 + lrow) * HDIM + k0 + 8 * g);
                acc[fn] = __builtin_amdgcn_mfma_f32_16x16x32_f16(a, b, acc[fn], 0, 0, 0);
            }
        }
#pragma unroll
        for (int fn = 0; fn < 2; ++fn) {
            int col = fn * 16 + lrow;
            float bcv = bc[col];
#pragma unroll
            for (int r = 0; r < 4; ++r) {
                int node = node0 + g * 4 + r;
                if (node < n) out[(size_t)node * CDIM + col] = acc[fn][r] + bcv;
            }
        }
    }
}

// ---------------- launch ----------------

extern "C" void kernel_launch(void* const* d_in, const int* in_sizes, int n_in,
                              void* d_out, int out_size, void* d_ws, size_t ws_size,
                              hipStream_t stream) {
    const float* X  = (const float*)d_in[0];
    const int*   ei = (const int*)d_in[1];
    const float* W1 = (const float*)d_in[2];
    const float* b1 = (const float*)d_in[3];
    const float* W2 = (const float*)d_in[4];
    const float* b2 = (const float*)d_in[5];
    const float* Wc = (const float*)d_in[6];
    const float* bc = (const float*)d_in[7];
    float* out = (float*)d_out;

    const int n = in_sizes[0] / IN_DIM;   // 100000
    const int e = in_sizes[1] / 2;        // 1600000
    const int* src = ei;
    const int* dst = ei + e;
    const int nsr = (n + NSUB - 1) / NSUB;  // sub-range size (196)

    // workspace layout
    char* ws = (char*)d_ws;
    auto align = [](size_t x) { return (x + 255) & ~(size_t)255; };
    size_t off = 0;
    float* dinv   = (float*)(ws + off); off += align((size_t)n * 4);
    int* row_ptr  = (int*)(ws + off);   off += align((size_t)(n + 1) * 4);
    int* cnt512   = (int*)(ws + off);   off += align(512 * 4);
    int* rp512    = (int*)(ws + off);   off += align(513 * 4);
    int* rcur512  = (int*)(ws + off);   off += align(512 * 4);
    long long* parts = (long long*)(ws + off); off += align((size_t)e * 8);
    int* csr_src  = (int*)(ws + off);   off += align((size_t)e * 4);
    unsigned short* w1t = (unsigned short*)(ws + off); off += align((size_t)IN_DIM * HDIM * 2);
    unsigned short* w2t = (unsigned short*)(ws + off); off += align((size_t)HDIM * HDIM * 2);
    unsigned short* wct = (unsigned short*)(ws + off); off += align((size_t)HDIM * CDIM * 2);
    __half* bufAh = (__half*)(ws + off); off += align((size_t)n * HDIM * 2);
    __half* bufBh = (__half*)(ws + off); off += align((size_t)n * HDIM * 2);

    // ---- weights (one launch) ----
    wconv_all_kernel<<<(IN_DIM * HDIM + HDIM * HDIM + HDIM * CDIM + 255) / 256, 256, 0, stream>>>(
        W1, W2, Wc, w1t, w2t, wct);

    // ---- hierarchical CSR build (shared by both layers) ----
    zero512_kernel<<<2, 256, 0, stream>>>(cnt512);
    hist512_kernel<<<256, 256, 0, stream>>>(dst, cnt512, e, nsr);
    scan512_kernel<<<1, 256, 0, stream>>>(cnt512, rp512, rcur512, e);
    part512_kernel<<<512, 256, 0, stream>>>(src, dst, rcur512, parts, e, nsr);
    sortplace_kernel<<<NSUB, 256, 0, stream>>>(parts, rp512, row_ptr, csr_src, dinv, n, nsr);

    const int gBlocks = (n + 127) / 128;
    const int nb_g = (n + 3) / 4;

    // layer 1: fp32 X -> fp16 h
    gemm_f16_kernel<128, false, false, true><<<gBlocks, 256, 0, stream>>>(X, w1t, nullptr, bufAh, n, IN_DIM);
    gather_kernel<<<nb_g, 256, 0, stream>>>(bufAh, row_ptr, csr_src, dinv, b1, bufBh, n);

    // layer 2 transform: fp16 -> fp16
    gemm_f16_kernel<128, true, false, true><<<gBlocks, 256, 0, stream>>>(bufBh, w2t, nullptr, bufAh, n, HDIM);

    // layer 2 aggregate + relu + classifier (fused), fp32 out
    gather_cls_kernel<<<(n + 15) / 16, 256, 0, stream>>>(bufAh, row_ptr, csr_src, dinv, b2, wct, bc, out, n);
}